// Round 2
// baseline (218.095 us; speedup 1.0000x reference)
//
#include <hip/hip_runtime.h>
#include <math.h>

#define D_DIM 128
#define K_DIM 64
#define R_DIM 8
#define B_DIM 8192

// Workspace layout (float offsets):
//   tbl : [K][D][12]  (-0.5*s_inv, h=m*s_inv, W[0..7], pad, pad)   k-major, 48B/entry
//   q   : [K][8]
//   c0  : [K]
//   part: [B][4][2]   per-(b, kgroup) partial (max, sumexp)
#define WS_TBL  0
#define WS_Q    (K_DIM * D_DIM * 12)
#define WS_C0   (WS_Q + K_DIM * R_DIM)
#define WS_PART (WS_C0 + K_DIM)

// ---------------------------------------------------------------------------
// Per-k precompute. Grid = K blocks, 128 threads (=D).
// Round-2 fix: lar mean via parallel reduction (was 64 serial global loads).
// ---------------------------------------------------------------------------
__global__ __launch_bounds__(128) void precomp_kernel(
    const float* __restrict__ m, const float* __restrict__ delta,
    const float* __restrict__ U, const float* __restrict__ lar,
    float* __restrict__ ws) {
  const int k = blockIdx.x;
  const int d = threadIdx.x;  // 0..127

  __shared__ float U_l[D_DIM][R_DIM];
  __shared__ float V_l[D_DIM][R_DIM];
  __shared__ float W_l[D_DIM][R_DIM];
  __shared__ float m_l[D_DIM];
  __shared__ float red[64];                 // Mcap entries (8x8)
  __shared__ float Linv_s[R_DIM][R_DIM];
  __shared__ float redA[D_DIM], redB[D_DIM], redC[D_DIM];

  const float dl    = delta[k * D_DIM + d];
  const float s_inv = expf(-dl);            // 1/exp(delta)
  const float mv    = m[k * D_DIM + d];
  m_l[d] = mv;
  const float* Up = U + (size_t)(k * D_DIM + d) * R_DIM;
#pragma unroll
  for (int r = 0; r < R_DIM; ++r) {
    float u = Up[r];
    U_l[d][r] = u;
    V_l[d][r] = u * s_inv;
  }
  redA[d] = dl;                       // sum(delta) = logdet of diag part
  redB[d] = mv * mv * s_inv;          // sum(m^2 * S_inv)
  redC[d] = (d < K_DIM) ? lar[d] : 0.f;  // parallel lar mean
  __syncthreads();

  // Mcap[r][s] = I + sum_d U[d,r]*V[d,s]
  if (d < 64) {
    const int r = d >> 3, s = d & 7;
    float acc = (r == s) ? 1.0f : 0.0f;
    for (int dd = 0; dd < D_DIM; ++dd) acc += U_l[dd][r] * V_l[dd][s];
    red[d] = acc;
  }
  __syncthreads();

  for (int off = 64; off > 0; off >>= 1) {
    if (d < off) {
      redA[d] += redA[d + off];
      redB[d] += redB[d + off];
      redC[d] += redC[d + off];
    }
    __syncthreads();
  }

  if (d == 0) {
    // 8x8 Cholesky of Mcap (well-conditioned: ~I + O(1e-3))
    float Lm[8][8];
    for (int i = 0; i < 8; ++i)
      for (int j = 0; j <= i; ++j) {
        float sum = red[i * 8 + j];
        for (int p2 = 0; p2 < j; ++p2) sum -= Lm[i][p2] * Lm[j][p2];
        Lm[i][j] = (i == j) ? sqrtf(sum) : sum / Lm[j][j];
      }
    float ld = 0.f;
    for (int i = 0; i < 8; ++i) ld += logf(Lm[i][i]);
    // invert lower-triangular L
    float Li[8][8];
    for (int i = 0; i < 8; ++i)
      for (int j = 0; j < 8; ++j) Li[i][j] = 0.f;
    for (int j = 0; j < 8; ++j) {
      Li[j][j] = 1.0f / Lm[j][j];
      for (int i = j + 1; i < 8; ++i) {
        float sum = 0.f;
        for (int p2 = j; p2 < i; ++p2) sum += Lm[i][p2] * Li[p2][j];
        Li[i][j] = -sum / Lm[i][i];
      }
    }
    for (int i = 0; i < 8; ++i)
      for (int j = 0; j < 8; ++j) Linv_s[i][j] = Li[i][j];

    const float mean = redC[0] * (1.0f / K_DIM);
    const float log_alpha = (lar[k] - mean);     // / eps, eps = 1
    const float logdetS   = redA[0] + 2.0f * ld;
    const float LOG2PI = 1.8378770664093453f;
    const float log_norm = 0.5f * ((float)D_DIM * LOG2PI + logdetS);
    ws[WS_C0 + k] = log_alpha - log_norm - 0.5f * redB[0];
  }
  __syncthreads();

  // W[d][r] = sum_{s<=r} V[d][s] * Linv[r][s]   (W = V * L^-T)
  float Wr[R_DIM];
#pragma unroll
  for (int r = 0; r < R_DIM; ++r) {
    float acc = 0.f;
    for (int s2 = 0; s2 <= r; ++s2) acc += V_l[d][s2] * Linv_s[r][s2];
    Wr[r] = acc;
    W_l[d][r] = acc;
  }

  // k-major table entry, 12 floats (48B, 16B-aligned)
  float* te = ws + WS_TBL + (size_t)(k * D_DIM + d) * 12;
  te[0] = -0.5f * s_inv;
  te[1] = mv * s_inv;
#pragma unroll
  for (int r = 0; r < R_DIM; ++r) te[2 + r] = Wr[r];
  te[10] = 0.f; te[11] = 0.f;
  __syncthreads();

  // q[k][r] = sum_d W[d][r] * m[d]
  if (d < R_DIM) {
    float acc = 0.f;
    for (int dd = 0; dd < D_DIM; ++dd) acc += W_l[dd][d] * m_l[dd];
    ws[WS_Q + k * R_DIM + d] = acc;
  }
}

// ---------------------------------------------------------------------------
// Main kernel: lane = b-row, wave = one k. Table reads are wave-uniform
// (one 40B fetch per wave per d, amortized over 64 lanes). 1024 threads =
// 16 waves = 16 k's per block; grid = 128 rowtiles x 4 kgroups = 512 blocks
// = 2 blocks/CU = 32 waves/CU.
// ---------------------------------------------------------------------------
__global__ __launch_bounds__(1024, 8) void logz_main(
    const float* __restrict__ y, const float* __restrict__ ws,
    float* __restrict__ part) {
  const int tid  = threadIdx.x;
  const int lane = tid & 63;
  const int wave = tid >> 6;          // 0..15
  const int rt   = blockIdx.x >> 2;   // 0..127
  const int kg   = blockIdx.x & 3;    // 0..3
  const int k    = kg * 16 + wave;
  const int b    = rt * 64 + lane;

  const float*  __restrict__ t  = ws + WS_TBL + (size_t)k * (D_DIM * 12);
  const float4* __restrict__ t4 = (const float4*)t;
  const float2* __restrict__ t2 = (const float2*)t;
  const float4* __restrict__ y4 = (const float4*)(y + (size_t)b * D_DIM);

  float g = 0.f;
  float p0 = 0.f, p1 = 0.f, p2 = 0.f, p3 = 0.f;
  float p4 = 0.f, p5 = 0.f, p6 = 0.f, p7 = 0.f;

#pragma unroll 2
  for (int d4 = 0; d4 < D_DIM / 4; ++d4) {
    const float4 yv = y4[d4];
#pragma unroll
    for (int j = 0; j < 4; ++j) {
      const int d = d4 * 4 + j;
      const float4 A  = t4[d * 3];        // (-0.5*s_inv, h, w0, w1)
      const float4 Bv = t4[d * 3 + 1];    // w2..w5
      const float2 Cv = t2[d * 6 + 4];    // w6, w7
      const float yd = (j == 0) ? yv.x : (j == 1) ? yv.y : (j == 2) ? yv.z : yv.w;
      const float tmp = fmaf(A.x, yd, A.y);   // h - 0.5*s_inv*y
      g  = fmaf(yd, tmp, g);
      p0 = fmaf(yd, A.z,  p0);
      p1 = fmaf(yd, A.w,  p1);
      p2 = fmaf(yd, Bv.x, p2);
      p3 = fmaf(yd, Bv.y, p3);
      p4 = fmaf(yd, Bv.z, p4);
      p5 = fmaf(yd, Bv.w, p5);
      p6 = fmaf(yd, Cv.x, p6);
      p7 = fmaf(yd, Cv.y, p7);
    }
  }

  const float4 q0 = ((const float4*)(ws + WS_Q))[k * 2];
  const float4 q1 = ((const float4*)(ws + WS_Q))[k * 2 + 1];
  const float cv  = ws[WS_C0 + k];

  float d0 = p0 - q0.x, d1 = p1 - q0.y, d2 = p2 - q0.z, d3 = p3 - q0.w;
  float d4v = p4 - q1.x, d5 = p5 - q1.y, d6 = p6 - q1.z, d7 = p7 - q1.w;
  float ss = d0*d0 + d1*d1 + d2*d2 + d3*d3 + d4v*d4v + d5*d5 + d6*d6 + d7*d7;
  const float val = cv + g + 0.5f * ss;

  __shared__ float vals[16][64];
  vals[wave][lane] = val;
  __syncthreads();

  if (tid < 64) {
    float v[16];
    float mx = -INFINITY;
#pragma unroll
    for (int w = 0; w < 16; ++w) {
      v[w] = vals[w][tid];
      mx = fmaxf(mx, v[w]);
    }
    float s = 0.f;
#pragma unroll
    for (int w = 0; w < 16; ++w) s += expf(v[w] - mx);
    float* pp = part + ((size_t)(rt * 64 + tid) * 4 + kg) * 2;
    pp[0] = mx;
    pp[1] = s;
  }
}

// ---------------------------------------------------------------------------
// Combine 4 kgroup-partials per b: out[b] = m + log(sum s_i * exp(m_i - m))
// ---------------------------------------------------------------------------
__global__ __launch_bounds__(256) void reduce_kernel(
    const float* __restrict__ part, float* __restrict__ out) {
  const int b = blockIdx.x * 256 + threadIdx.x;
  const float4 a0 = ((const float4*)part)[b * 2];      // m0,s0,m1,s1
  const float4 a1 = ((const float4*)part)[b * 2 + 1];  // m2,s2,m3,s3
  float mx = fmaxf(fmaxf(a0.x, a0.z), fmaxf(a1.x, a1.z));
  float s = a0.y * expf(a0.x - mx) + a0.w * expf(a0.z - mx)
          + a1.y * expf(a1.x - mx) + a1.w * expf(a1.z - mx);
  out[b] = mx + logf(s);
}

extern "C" void kernel_launch(void* const* d_in, const int* in_sizes, int n_in,
                              void* d_out, int out_size, void* d_ws, size_t ws_size,
                              hipStream_t stream) {
  const float* y     = (const float*)d_in[0];
  const float* m     = (const float*)d_in[1];
  const float* delta = (const float*)d_in[2];
  const float* U     = (const float*)d_in[3];
  const float* lar   = (const float*)d_in[4];
  float* out = (float*)d_out;
  float* ws  = (float*)d_ws;

  precomp_kernel<<<K_DIM, 128, 0, stream>>>(m, delta, U, lar, ws);
  logz_main<<<512, 1024, 0, stream>>>(y, ws, ws + WS_PART);
  reduce_kernel<<<B_DIM / 256, 256, 0, stream>>>(ws + WS_PART, out);
}

// Round 3
// 94.729 us; speedup vs baseline: 2.3023x; 2.3023x over previous
//
#include <hip/hip_runtime.h>
#include <math.h>

#define D_DIM 128
#define K_DIM 64
#define R_DIM 8
#define B_DIM 8192
#define KG    4      // k-groups (blocks in k)
#define KPB   16     // k per block
#define ROWS  64     // b-rows per block
#define CHUNK 32     // d per LDS chunk
#define ENT   12     // floats per table entry: [w0..w7, -0.5*s_inv, h', 0, 0]

// ws layout (float offsets):
//   tbl : [KG][D][KPB][ENT]  = 98304 floats
//   c0  : [K]
//   part: [B][KG][2]
#define WS_TBL  0
#define WS_C0   (KG * D_DIM * KPB * ENT)
#define WS_PART (WS_C0 + K_DIM)

// ---------------------------------------------------------------------------
// Per-k precompute. Grid = K blocks, 128 threads (=D).
// Round-3 fixes: (a) Cholesky/inverse fully statically unrolled (constant
// indices -> registers, no scratch spill); (b) fold q into h' and c0' so the
// main kernel needs no q:  logit = c0' + sum_d y*(h' - 0.5*s*y) + 0.5*||W^T y||^2
// ---------------------------------------------------------------------------
__global__ __launch_bounds__(128) void precomp_kernel(
    const float* __restrict__ m, const float* __restrict__ delta,
    const float* __restrict__ U, const float* __restrict__ lar,
    float* __restrict__ ws) {
  const int k = blockIdx.x;
  const int d = threadIdx.x;  // 0..127

  __shared__ float U_l[D_DIM][R_DIM];
  __shared__ float V_l[D_DIM][R_DIM];
  __shared__ float W_l[D_DIM][R_DIM];
  __shared__ float m_l[D_DIM];
  __shared__ float red[64];
  __shared__ float Linv_s[R_DIM][R_DIM];
  __shared__ float q_s[R_DIM];
  __shared__ float c0_s[1];
  __shared__ float redA[D_DIM], redB[D_DIM], redC[D_DIM];

  const float dl    = delta[k * D_DIM + d];
  const float s_inv = expf(-dl);
  const float mv    = m[k * D_DIM + d];
  m_l[d] = mv;
  const float* Up = U + (size_t)(k * D_DIM + d) * R_DIM;
#pragma unroll
  for (int r = 0; r < R_DIM; ++r) {
    float u = Up[r];
    U_l[d][r] = u;
    V_l[d][r] = u * s_inv;
  }
  redA[d] = dl;
  redB[d] = mv * mv * s_inv;
  redC[d] = (d < K_DIM) ? lar[d] : 0.f;
  __syncthreads();

  if (d < 64) {
    const int r = d >> 3, s = d & 7;
    float acc = (r == s) ? 1.0f : 0.0f;
#pragma unroll 8
    for (int dd = 0; dd < D_DIM; ++dd) acc += U_l[dd][r] * V_l[dd][s];
    red[d] = acc;
  }
  __syncthreads();

  for (int off = 64; off > 0; off >>= 1) {
    if (d < off) {
      redA[d] += redA[d + off];
      redB[d] += redB[d + off];
      redC[d] += redC[d + off];
    }
    __syncthreads();
  }

  if (d == 0) {
    // 8x8 Cholesky, fully static after unroll (no dynamic array indexing)
    float Lm[8][8];
#pragma unroll
    for (int i = 0; i < 8; ++i) {
#pragma unroll
      for (int j = 0; j < 8; ++j) {
        if (j > i) continue;
        float sum = red[i * 8 + j];
#pragma unroll
        for (int p = 0; p < 8; ++p)
          if (p < j) sum -= Lm[i][p] * Lm[j][p];
        if (i == j) Lm[i][i] = sqrtf(sum);
        else        Lm[i][j] = sum / Lm[j][j];
      }
    }
    float ld = 0.f;
#pragma unroll
    for (int i = 0; i < 8; ++i) ld += logf(Lm[i][i]);

    float Li[8][8];
#pragma unroll
    for (int i = 0; i < 8; ++i)
#pragma unroll
      for (int j = 0; j < 8; ++j) Li[i][j] = 0.f;
#pragma unroll
    for (int j = 0; j < 8; ++j) {
      Li[j][j] = 1.0f / Lm[j][j];
#pragma unroll
      for (int i = 0; i < 8; ++i) {
        if (i <= j) continue;
        float sum = 0.f;
#pragma unroll
        for (int p = 0; p < 8; ++p)
          if (p >= j && p < i) sum += Lm[i][p] * Li[p][j];
        Li[i][j] = -sum / Lm[i][i];
      }
    }
#pragma unroll
    for (int i = 0; i < 8; ++i)
#pragma unroll
      for (int j = 0; j < 8; ++j) Linv_s[i][j] = Li[i][j];

    const float mean = redC[0] * (1.0f / K_DIM);
    const float log_alpha = lar[k] - mean;       // /eps, eps=1
    const float logdetS = redA[0] + 2.0f * ld;   // sum(delta) + 2*sum(log L_ii)
    const float LOG2PI = 1.8378770664093453f;
    const float log_norm = 0.5f * ((float)D_DIM * LOG2PI + logdetS);
    c0_s[0] = log_alpha - log_norm - 0.5f * redB[0];
  }
  __syncthreads();

  // W[d][r] = sum_{s<=r} V[d][s] * Linv[r][s]
  float Wr[R_DIM];
#pragma unroll
  for (int r = 0; r < R_DIM; ++r) {
    float acc = 0.f;
#pragma unroll
    for (int s2 = 0; s2 < R_DIM; ++s2)
      if (s2 <= r) acc += V_l[d][s2] * Linv_s[r][s2];
    Wr[r] = acc;
    W_l[d][r] = acc;
  }
  __syncthreads();

  // q[r] = sum_d W[d][r] * m[d]
  if (d < R_DIM) {
    float acc = 0.f;
#pragma unroll 8
    for (int dd = 0; dd < D_DIM; ++dd) acc += W_l[dd][d] * m_l[dd];
    q_s[d] = acc;
  }
  __syncthreads();

  // h' = m*s_inv - sum_r q_r * W_r ;  entry = [w0..w7, -0.5*s_inv, h', 0, 0]
  float hp = mv * s_inv;
#pragma unroll
  for (int r = 0; r < R_DIM; ++r) hp -= q_s[r] * Wr[r];

  float* e = ws + WS_TBL +
             (size_t)(((k >> 4) * D_DIM + d) * KPB + (k & 15)) * ENT;
#pragma unroll
  for (int r = 0; r < R_DIM; ++r) e[r] = Wr[r];
  e[8]  = -0.5f * s_inv;
  e[9]  = hp;
  e[10] = 0.f;
  e[11] = 0.f;

  if (d == 0) {
    float qq = 0.f;
#pragma unroll
    for (int r = 0; r < R_DIM; ++r) qq += q_s[r] * q_s[r];
    ws[WS_C0 + k] = c0_s[0] + 0.5f * qq;   // c0' = c0 + 0.5*||q||^2
  }
}

// ---------------------------------------------------------------------------
// Main kernel: block = 512 thr = 8 waves; covers 64 rows x 16 k.
// lane: ki = lane&15 (k), bi = lane>>4; each lane handles 2 rows (bi, bi+4
// within its wave's 8-row group). Table slice + y staged through LDS in
// 32-d chunks; table via global_load_lds width=16.
// Grid = 128 rowtiles x 4 kgroups = 512 blocks (2/CU, 16 waves/CU).
// ---------------------------------------------------------------------------
__global__ __launch_bounds__(512, 4) void logz_main(
    const float* __restrict__ y, const float* __restrict__ ws,
    float* __restrict__ part) {
  __shared__ float sT[CHUNK * KPB * ENT];   // 6144 floats, [dl][ki][ENT]
  __shared__ float sY[ROWS * 36];           // padded rows: bank-conflict-free
  __shared__ float vals[ROWS * 17];         // [row][ki], stride 17

  const int tid  = threadIdx.x;
  const int lane = tid & 63;
  const int wv   = tid >> 6;        // 0..7
  const int rt   = (int)blockIdx.x >> 2;
  const int kg   = (int)blockIdx.x & 3;
  const int ki   = lane & 15;
  const int bi   = lane >> 4;       // 0..3
  const int rowA = wv * 8 + bi;     // local rows
  const int rowB = rowA + 4;
  const int r0   = rt * ROWS;       // global row base

  const float* __restrict__ tblG = ws + WS_TBL + (size_t)kg * (D_DIM * KPB * ENT);

  float gA = 0.f, gB = 0.f;
  float pA[8], pB[8];
#pragma unroll
  for (int r = 0; r < 8; ++r) { pA[r] = 0.f; pB[r] = 0.f; }

  const int yrow = tid >> 3, yseg = tid & 7;   // y staging assignment

  for (int c = 0; c < D_DIM / CHUNK; ++c) {
    __syncthreads();   // previous chunk's compute done before overwrite
    // ---- stage table chunk (24 KB): wave wv copies 3 x 1KB via global_load_lds
    {
      const float* src = tblG + (size_t)c * (CHUNK * KPB * ENT);
#pragma unroll
      for (int j = 0; j < 3; ++j) {
        const int off = (wv * 3 + j) * 256;   // floats
        __builtin_amdgcn_global_load_lds(
            (const __attribute__((address_space(1))) void*)(src + off + lane * 4),
            (__attribute__((address_space(3))) void*)(sT + off),
            16, 0, 0);
      }
    }
    // ---- stage y chunk (8 KB): thread -> (row, 4-float segment), coalesced
    {
      const float4 v = *(const float4*)(y + (size_t)(r0 + yrow) * D_DIM
                                          + c * CHUNK + yseg * 4);
      *(float4*)(sY + yrow * 36 + yseg * 4) = v;
    }
    __syncthreads();
    // ---- compute 32 d
#pragma unroll
    for (int d4 = 0; d4 < CHUNK / 4; ++d4) {
      const float4 ya4 = *(const float4*)(sY + rowA * 36 + d4 * 4);
      const float4 yb4 = *(const float4*)(sY + rowB * 36 + d4 * 4);
#pragma unroll
      for (int j = 0; j < 4; ++j) {
        const float* e = sT + ((d4 * 4 + j) * KPB + ki) * ENT;
        const float4 w0 = *(const float4*)(e);
        const float4 w1 = *(const float4*)(e + 4);
        const float2 sh = *(const float2*)(e + 8);   // (-0.5*s_inv, h')
        const float ya = (j == 0) ? ya4.x : (j == 1) ? ya4.y : (j == 2) ? ya4.z : ya4.w;
        const float yb = (j == 0) ? yb4.x : (j == 1) ? yb4.y : (j == 2) ? yb4.z : yb4.w;
        gA = fmaf(ya, fmaf(sh.x, ya, sh.y), gA);
        gB = fmaf(yb, fmaf(sh.x, yb, sh.y), gB);
        pA[0] = fmaf(ya, w0.x, pA[0]);  pB[0] = fmaf(yb, w0.x, pB[0]);
        pA[1] = fmaf(ya, w0.y, pA[1]);  pB[1] = fmaf(yb, w0.y, pB[1]);
        pA[2] = fmaf(ya, w0.z, pA[2]);  pB[2] = fmaf(yb, w0.z, pB[2]);
        pA[3] = fmaf(ya, w0.w, pA[3]);  pB[3] = fmaf(yb, w0.w, pB[3]);
        pA[4] = fmaf(ya, w1.x, pA[4]);  pB[4] = fmaf(yb, w1.x, pB[4]);
        pA[5] = fmaf(ya, w1.y, pA[5]);  pB[5] = fmaf(yb, w1.y, pB[5]);
        pA[6] = fmaf(ya, w1.z, pA[6]);  pB[6] = fmaf(yb, w1.z, pB[6]);
        pA[7] = fmaf(ya, w1.w, pA[7]);  pB[7] = fmaf(yb, w1.w, pB[7]);
      }
    }
  }

  const float cv = ws[WS_C0 + kg * KPB + ki];
  float qa = pA[0]*pA[0] + pA[1]*pA[1] + pA[2]*pA[2] + pA[3]*pA[3]
           + pA[4]*pA[4] + pA[5]*pA[5] + pA[6]*pA[6] + pA[7]*pA[7];
  float qb = pB[0]*pB[0] + pB[1]*pB[1] + pB[2]*pB[2] + pB[3]*pB[3]
           + pB[4]*pB[4] + pB[5]*pB[5] + pB[6]*pB[6] + pB[7]*pB[7];
  const float vA = cv + gA + 0.5f * qa;
  const float vB = cv + gB + 0.5f * qb;

  vals[rowA * 17 + ki] = vA;
  vals[rowB * 17 + ki] = vB;
  __syncthreads();

  if (tid < 64) {
    float mx = -INFINITY;
#pragma unroll
    for (int j = 0; j < KPB; ++j) mx = fmaxf(mx, vals[tid * 17 + j]);
    float s = 0.f;
#pragma unroll
    for (int j = 0; j < KPB; ++j) s += expf(vals[tid * 17 + j] - mx);
    *(float2*)(part + ((size_t)(r0 + tid) * KG + kg) * 2) = make_float2(mx, s);
  }
}

// ---------------------------------------------------------------------------
// Combine 4 kgroup-partials per b.
// ---------------------------------------------------------------------------
__global__ __launch_bounds__(256) void reduce_kernel(
    const float* __restrict__ part, float* __restrict__ out) {
  const int b = blockIdx.x * 256 + threadIdx.x;
  const float4 a0 = ((const float4*)part)[b * 2];
  const float4 a1 = ((const float4*)part)[b * 2 + 1];
  float mx = fmaxf(fmaxf(a0.x, a0.z), fmaxf(a1.x, a1.z));
  float s = a0.y * expf(a0.x - mx) + a0.w * expf(a0.z - mx)
          + a1.y * expf(a1.x - mx) + a1.w * expf(a1.z - mx);
  out[b] = mx + logf(s);
}

extern "C" void kernel_launch(void* const* d_in, const int* in_sizes, int n_in,
                              void* d_out, int out_size, void* d_ws, size_t ws_size,
                              hipStream_t stream) {
  const float* y     = (const float*)d_in[0];
  const float* m     = (const float*)d_in[1];
  const float* delta = (const float*)d_in[2];
  const float* U     = (const float*)d_in[3];
  const float* lar   = (const float*)d_in[4];
  float* out = (float*)d_out;
  float* ws  = (float*)d_ws;

  precomp_kernel<<<K_DIM, 128, 0, stream>>>(m, delta, U, lar, ws);
  logz_main<<<(B_DIM / ROWS) * KG, 512, 0, stream>>>(y, ws, ws + WS_PART);
  reduce_kernel<<<B_DIM / 256, 256, 0, stream>>>(ws + WS_PART, out);
}